// Round 16
// baseline (155.068 us; speedup 1.0000x reference)
//
#include <hip/hip_runtime.h>
#include <hip/hip_bf16.h>

// Problem constants (fixed shapes from the reference)
#define DIN   2048
#define DOUT  2048
#define NTOK  2048
#define NE    8
#define TOPK  2
#define NK    (NTOK*TOPK)        // 4096 flat (token,slot) rows
#define BM    384
#define BN    128
#define BK    32
#define NKT   (DIN/BK)           // 64 K-steps
#define MAXMT (NK/BM + NE)       // 10+8 = 18 worst-case M-tiles (Σceil(cnt/384) ≤ 18)
#define NTN   (DOUT/BN)          // 16 N-tiles
#define NBLK  (MAXMT*NTN)        // 288 (multiple of 8); ~256 real jobs = 1/CU
#define WEL (NE*DOUT*DIN)        // 33554432 weight elements
#define XEL (NTOK*DIN)           // 4194304 input elements

typedef unsigned short u16;
typedef __attribute__((ext_vector_type(8))) short bf16x8;
typedef __attribute__((ext_vector_type(4))) float f32x4;

// fp32 -> bf16 pair pack: round-half-away (add 0x8000), v_perm grabs high halves.
__device__ __forceinline__ unsigned pack2rn(float a, float b) {
    union { float f; unsigned u; } x, y; x.f = a; y.f = b;
    return __builtin_amdgcn_perm(y.u + 0x8000u, x.u + 0x8000u, 0x07060302u);
}

// async global -> LDS, 16B/lane (wave-uniform LDS base; HW adds lane*16; global addr per-lane)
__device__ __forceinline__ void gl_lds16(const void* g, void* l) {
    __builtin_amdgcn_global_load_lds(
        (const __attribute__((address_space(1))) void*)g,
        (__attribute__((address_space(3)))       void*)l, 16, 0, 0);
}

// ---------------- Pass 1: fp32 -> bf16 convert (INPUTS ONLY, ~25 MB) ----------------
__global__ __launch_bounds__(256) void cvt_x(
    const float* __restrict__ x, u16* __restrict__ xbf)
{
    const size_t nch = (size_t)XEL / 8;
    for (size_t c = (size_t)blockIdx.x * blockDim.x + threadIdx.x; c < nch;
         c += (size_t)gridDim.x * blockDim.x) {
        size_t off = c * 8;
        float4 f0 = *(const float4*)(x + off);
        float4 f1 = *(const float4*)(x + off + 4);
        uint4 pk;
        pk.x = pack2rn(f0.x, f0.y); pk.y = pack2rn(f0.z, f0.w);
        pk.z = pack2rn(f1.x, f1.y); pk.w = pack2rn(f1.z, f1.w);
        *(uint4*)(xbf + off) = pk;
    }
}

// ---------------- Pass 2: 384x128 grouped GEMM (BK=32), fused W cvt ----------------
// Makespan/step-count optimum: BM=384 -> each expert (cnt~512) = exactly 2
// M-tiles -> ~256 real jobs = ONE job per CU, single scheduling round (R10 had
// 288 jobs: 32 CUs ran 2 jobs = 128 K-steps on the critical path; here 64).
// Body/choreography = R10 verbatim (fp32-B reg-staged + fused pack; cvt_x only).
__global__ __launch_bounds__(512, 2) void moe_gemm_384(
    const u16*   __restrict__ xb,          // [NTOK][DIN] bf16
    const float* __restrict__ wf,          // [NE][DOUT][DIN] fp32
    const int*   __restrict__ sorted_scattered_idxs,
    const int*   __restrict__ expert_offsets,
    const float* __restrict__ gates,
    float*       __restrict__ out)
{
    __shared__ u16 As[2][BM * BK];         // 24 KB each
    __shared__ u16 Bs[2][BN * BK];         // 8 KB each
    __shared__ int   s_tok[BM];
    __shared__ float s_gate[BM];

    // Bijective XCD swizzle (288 = 8*36): n0 fastest (16 jobs share an A-panel
    // on one XCD), then mt.
    const int bid = blockIdx.x;
    const int swz = (bid & 7) * (NBLK / 8) + (bid >> 3);
    const int n0  = (swz & (NTN - 1)) * BN;
    const int mt  = swz >> 4;

    int e = -1, m0 = 0, cnt = 0;
    {
        int acc0 = 0, prev = 0;
        for (int i = 0; i < NE; ++i) {
            int end = expert_offsets[i];
            int c = end - prev;
            int t = (c + BM - 1) / BM;
            if (mt < acc0 + t) {
                e = i; m0 = prev + (mt - acc0) * BM;
                cnt = end - m0; if (cnt > BM) cnt = BM;
                break;
            }
            acc0 += t; prev = end;
        }
    }
    if (e < 0) return;   // ghost tile: uniform exit before any barrier

    const int tid = threadIdx.x;
    if (tid < BM) {
        int idx = (tid < cnt) ? (m0 + tid) : m0;   // clamp ragged rows to valid gather
        int p = sorted_scattered_idxs[idx];
        s_tok[tid]  = p;
        s_gate[tid] = gates[p];
    }
    __syncthreads();

    const int wid = tid >> 6, lane = tid & 63;

    // ---- A staging (bf16, 3 gload_lds/thread/K-step), source-side swizzle:
    // LDS[r][y] = G[y ^ ((r>>1)&3)] (rule 21; LDS linear). Chunk c = s*512 +
    // wid*64 + lane -> row = s*128 + wid*16 + (lane>>2), ch = lane&3.
    const int cga = (lane & 3) ^ ((lane >> 3) & 3);    // (row>>1)&3 == (lane>>3)&3
    const u16* aS[3];
    int adst[3];
    #pragma unroll
    for (int s = 0; s < 3; ++s) {
        int r = s * 128 + wid * 16 + (lane >> 2);
        aS[s]   = xb + (size_t)(s_tok[r] >> 1) * DIN + cga * 8;
        adst[s] = (s * 128 + wid * 16) * BK;           // wave-uniform u16 base
    }

    // ---- B staging (fp32 weight, reg-staged, write-side swizzle) — R10 verbatim.
    const int brow = tid >> 2;                         // 0..127
    const int bch  = tid & 3;
    const int bcg  = bch ^ ((brow >> 1) & 3);
    const float* bF = wf + (size_t)e * DOUT * DIN + (size_t)(n0 + brow) * DIN + bch * 8;
    const int bwr = brow * BK + bcg * 8;               // u16 LDS offset

    // ---- fragment geometry: 8 waves 2M x 4N; wave out 192x32 at (wr*192, wc*32)
    const int wr = wid >> 2, wc = wid & 3;
    const int lr = lane & 15, g = lane >> 4;
    const int xch = (g ^ ((lr >> 1) & 3)) * 8;         // swizzled k-chunk (u16 units)
    int aoff[12], boff[2];
    #pragma unroll
    for (int mi = 0; mi < 12; ++mi) aoff[mi] = (wr * 192 + mi * 16 + lr) * BK + xch;
    #pragma unroll
    for (int n = 0; n < 2; ++n)     boff[n]  = (wc * 32 + n * 16 + lr) * BK + xch;

    f32x4 acc[12][2];
    #pragma unroll
    for (int mi = 0; mi < 12; ++mi)
        #pragma unroll
        for (int n = 0; n < 2; ++n) acc[mi][n] = (f32x4)0.0f;

    float4 pb0, pb1;   // in-flight fp32 B regs (8 floats)

#define STGA(buf, t)                                                          \
    {                                                                         \
        const int ko = (t) * BK;                                              \
        gl_lds16(aS[0] + ko, &As[buf][adst[0]]);                              \
        gl_lds16(aS[1] + ko, &As[buf][adst[1]]);                              \
        gl_lds16(aS[2] + ko, &As[buf][adst[2]]);                              \
    }

#define BGLB(t)                                                               \
    {                                                                         \
        const int ko = (t) * BK;                                              \
        pb0 = *(const float4*)(bF + ko);                                      \
        pb1 = *(const float4*)(bF + ko + 4);                                  \
    }

#define BPACK(buf)                                                            \
    {                                                                         \
        uint4 w;                                                              \
        w.x = pack2rn(pb0.x, pb0.y); w.y = pack2rn(pb0.z, pb0.w);             \
        w.z = pack2rn(pb1.x, pb1.y); w.w = pack2rn(pb1.z, pb1.w);             \
        *(uint4*)(&Bs[buf][bwr]) = w;                                         \
    }

#define BODY(b)                                                               \
    {                                                                         \
        bf16x8 bfv[2], af[6], ag[6];                                          \
        bfv[0] = *(const bf16x8*)(&Bs[b][boff[0]]);                           \
        bfv[1] = *(const bf16x8*)(&Bs[b][boff[1]]);                           \
        _Pragma("unroll")                                                     \
        for (int mi = 0; mi < 6; ++mi)                                        \
            af[mi] = *(const bf16x8*)(&As[b][aoff[mi]]);                      \
        __builtin_amdgcn_s_setprio(1);                                        \
        _Pragma("unroll")                                                     \
        for (int mi = 0; mi < 6; ++mi) {                                      \
            acc[mi][0] = __builtin_amdgcn_mfma_f32_16x16x32_bf16(             \
                af[mi], bfv[0], acc[mi][0], 0, 0, 0);                         \
            acc[mi][1] = __builtin_amdgcn_mfma_f32_16x16x32_bf16(             \
                af[mi], bfv[1], acc[mi][1], 0, 0, 0);                         \
        }                                                                     \
        _Pragma("unroll")                                                     \
        for (int mi = 0; mi < 6; ++mi)                                        \
            ag[mi] = *(const bf16x8*)(&As[b][aoff[mi + 6]]);                  \
        _Pragma("unroll")                                                     \
        for (int mi = 0; mi < 6; ++mi) {                                      \
            acc[mi+6][0] = __builtin_amdgcn_mfma_f32_16x16x32_bf16(           \
                ag[mi], bfv[0], acc[mi+6][0], 0, 0, 0);                       \
            acc[mi+6][1] = __builtin_amdgcn_mfma_f32_16x16x32_bf16(           \
                ag[mi], bfv[1], acc[mi+6][1], 0, 0, 0);                       \
        }                                                                     \
        __builtin_amdgcn_s_setprio(0);                                        \
        __builtin_amdgcn_s_barrier();                                         \
    }

    // ---- prologue: tile 0 to LDS (single drain), tile 1 in flight (R10 verbatim)
    BGLB(0);
    STGA(0, 0);
    asm volatile("s_waitcnt vmcnt(0)" ::: "memory");
    __builtin_amdgcn_sched_barrier(0);
    BPACK(0);
    STGA(1, 1);
    BGLB(1);

    #pragma unroll 2
    for (int t = 0; t < NKT; ++t) {
        // own ds_write (BPACK at tail t-1 / prologue) retired before barrier
        asm volatile("s_waitcnt lgkmcnt(0)" ::: "memory");
        __builtin_amdgcn_s_barrier();
        BODY(t & 1);                           // ends with s_barrier
        // drain stage(t+1), issued one full body ago (latency hidden)
        asm volatile("s_waitcnt vmcnt(0)" ::: "memory");
        __builtin_amdgcn_sched_barrier(0);
        if (t + 1 < NKT) BPACK((t + 1) & 1);   // buf free: its readers done in BODY(t-1)
        if (t + 2 < NKT) { STGA(t & 1, t + 2); BGLB(t + 2); }
    }

#undef STGA
#undef BGLB
#undef BPACK
#undef BODY

    // ---- epilogue: out[token] += gate * y  (TOPK contributions accumulate)
    #pragma unroll
    for (int mi = 0; mi < 12; ++mi) {
        #pragma unroll
        for (int r = 0; r < 4; ++r) {
            int lrow = wr * 192 + mi * 16 + g * 4 + r;
            if (lrow < cnt) {
                int   p  = s_tok[lrow];
                float gf = s_gate[lrow];
                float* orow = out + (size_t)(p >> 1) * DOUT + n0 + wc * 32;
                #pragma unroll
                for (int n = 0; n < 2; ++n)
                    atomicAdd(orow + n * 16 + lr, gf * acc[mi][n][r]);
            }
        }
    }
}

// ---------------- Fallback: fully-fused fp32-in kernel (used if ws too small) ----------------
#define FBM 128
#define FBK 64
__global__ __launch_bounds__(256, 3) void moe_gemm_fused(
    const float* __restrict__ inputs, const float* __restrict__ weight,
    const int* __restrict__ sorted_scattered_idxs, const int* __restrict__ expert_offsets,
    const float* __restrict__ gates, float* __restrict__ out)
{
    __shared__ u16 As[FBM * FBK];
    __shared__ u16 Bs[FBM * FBK];
    __shared__ int   s_tok[FBM];
    __shared__ float s_gate[FBM];

    const int mt = blockIdx.y;
    const int n0 = blockIdx.x * FBM;
    int e = -1, m0 = 0, cnt = 0;
    {
        int acc = 0, prev = 0;
        for (int i = 0; i < NE; ++i) {
            int end = expert_offsets[i];
            int c = end - prev;
            int t = (c + FBM - 1) / FBM;
            if (mt < acc + t) {
                e = i; m0 = prev + (mt - acc) * FBM;
                cnt = end - m0; if (cnt > FBM) cnt = FBM;
                break;
            }
            acc += t; prev = end;
        }
    }
    if (e < 0) return;

    const int tid = threadIdx.x;
    if (tid < FBM) {
        int idx = (tid < cnt) ? (m0 + tid) : m0;
        int p = sorted_scattered_idxs[idx];
        s_tok[tid]  = p;
        s_gate[tid] = gates[p];
    }
    __syncthreads();

    const int ch  = tid & 7;
    const int r0  = tid >> 3;
    const int sch = ch ^ (r0 & 7);
    const float* wbase = weight + (size_t)e * DOUT * DIN;
    const float* ap[4]; const float* bp[4];
    #pragma unroll
    for (int i = 0; i < 4; ++i) {
        int r = r0 + 32 * i;
        ap[i] = inputs + (size_t)(s_tok[r] >> 1) * DIN + ch * 8;
        bp[i] = wbase + (size_t)(n0 + r) * DIN + ch * 8;
    }
    u16* aw = &As[r0 * FBK + sch * 8];
    u16* bw = &Bs[r0 * FBK + sch * 8];

    const int wid = tid >> 6, lane = tid & 63;
    const int wm = (wid >> 1) * 64, wn = (wid & 1) * 64;
    const int g  = lane >> 4, lr = lane & 15;

    f32x4 acc[4][4];
    #pragma unroll
    for (int i = 0; i < 4; ++i)
        #pragma unroll
        for (int j = 0; j < 4; ++j) acc[i][j] = (f32x4)0.0f;

    float4 pa[4][2], pb[4][2];
    #pragma unroll
    for (int i = 0; i < 4; ++i) {
        pa[i][0] = *(const float4*)(ap[i] + 0); pa[i][1] = *(const float4*)(ap[i] + 4);
        pb[i][0] = *(const float4*)(bp[i] + 0); pb[i][1] = *(const float4*)(bp[i] + 4);
    }
    for (int kt = 0; kt < DIN / FBK; ++kt) {
        __syncthreads();
        #pragma unroll
        for (int i = 0; i < 4; ++i) {
            uint4 va, vb;
            va.x = pack2rn(pa[i][0].x, pa[i][0].y); va.y = pack2rn(pa[i][0].z, pa[i][0].w);
            va.z = pack2rn(pa[i][1].x, pa[i][1].y); va.w = pack2rn(pa[i][1].z, pa[i][1].w);
            *(uint4*)(aw + i * 32 * FBK) = va;
            vb.x = pack2rn(pb[i][0].x, pb[i][0].y); vb.y = pack2rn(pb[i][0].z, pb[i][0].w);
            vb.z = pack2rn(pb[i][1].x, pb[i][1].y); vb.w = pack2rn(pb[i][1].z, pb[i][1].w);
            *(uint4*)(bw + i * 32 * FBK) = vb;
        }
        __syncthreads();
        if (kt + 1 < DIN / FBK) {
            const int kof = (kt + 1) * FBK;
            #pragma unroll
            for (int i = 0; i < 4; ++i) {
                pa[i][0] = *(const float4*)(ap[i] + kof); pa[i][1] = *(const float4*)(ap[i] + kof + 4);
                pb[i][0] = *(const float4*)(bp[i] + kof); pb[i][1] = *(const float4*)(bp[i] + kof + 4);
            }
        }
        #pragma unroll
        for (int ks = 0; ks < 2; ++ks) {
            bf16x8 a[4], b[4];
            #pragma unroll
            for (int i = 0; i < 4; ++i) {
                int ra = wm + i * 16 + lr; int ca = (ks * 4 + g) ^ (ra & 7);
                a[i] = *(const bf16x8*)(&As[ra * FBK + ca * 8]);
                int rb = wn + i * 16 + lr; int cb = (ks * 4 + g) ^ (rb & 7);
                b[i] = *(const bf16x8*)(&Bs[rb * FBK + cb * 8]);
            }
            #pragma unroll
            for (int i = 0; i < 4; ++i)
                #pragma unroll
                for (int j = 0; j < 4; ++j)
                    acc[i][j] = __builtin_amdgcn_mfma_f32_16x16x32_bf16(a[i], b[j], acc[i][j], 0, 0, 0);
        }
    }
    #pragma unroll
    for (int i = 0; i < 4; ++i) {
        #pragma unroll
        for (int j2 = 0; j2 < 4; ++j2) {
            int lrow = wm + i * 16 + g * 4 + j2;
            if (lrow < cnt) {
                int   p  = s_tok[lrow];
                float gf = s_gate[lrow];
                float* orow = out + (size_t)(p >> 1) * DOUT + n0 + wn;
                #pragma unroll
                for (int nf = 0; nf < 4; ++nf)
                    atomicAdd(orow + nf * 16 + lr, gf * acc[i][nf][j2]);
            }
        }
    }
}

extern "C" void kernel_launch(void* const* d_in, const int* in_sizes, int n_in,
                              void* d_out, int out_size, void* d_ws, size_t ws_size,
                              hipStream_t stream) {
    const float* inputs  = (const float*)d_in[0];
    const float* weight  = (const float*)d_in[1];
    const int*   ssi     = (const int*)d_in[4];
    const int*   eoff    = (const int*)d_in[6];
    const float* gates   = (const float*)d_in[7];
    float* out = (float*)d_out;

    hipMemsetAsync(out, 0, (size_t)out_size * sizeof(float), stream);

    const size_t need = (size_t)XEL * sizeof(u16);   // 8.4 MB (inputs only)
    if (ws_size >= need) {
        u16* xbf = (u16*)d_ws;
        cvt_x<<<1024, 256, 0, stream>>>(inputs, xbf);
        moe_gemm_384<<<NBLK, 512, 0, stream>>>(xbf, weight, ssi, eoff, gates, out);
    } else {
        dim3 grid(DOUT / FBM, NK / FBM + NE);
        moe_gemm_fused<<<grid, 256, 0, stream>>>(inputs, weight, ssi, eoff, gates, out);
    }
}

// Round 17
// 103.927 us; speedup vs baseline: 1.4921x; 1.4921x over previous
//
#include <hip/hip_runtime.h>
#include <hip/hip_bf16.h>

// Problem constants (fixed shapes from the reference)
#define DIN   2048
#define DOUT  2048
#define NTOK  2048
#define NE    8
#define TOPK  2
#define NK    (NTOK*TOPK)        // 4096 flat (token,slot) rows
#define BM    256
#define BN    128
#define BK    32
#define NKT   (DIN/BK)           // 64 K-steps
#define MAXMT (NK/BM + NE)       // 24 worst-case M-tiles = 8 XCDs x 3
#define NTN   (DOUT/BN)          // 16 N-tiles
#define NBLK  (MAXMT*NTN)        // 384 (multiple of 8)

#define WEL (NE*DOUT*DIN)        // 33554432 weight elements
#define XEL (NTOK*DIN)           // 4194304 input elements

typedef unsigned short u16;
typedef __attribute__((ext_vector_type(8))) short bf16x8;
typedef __attribute__((ext_vector_type(4))) float f32x4;

// fp32 -> bf16 pair pack: round-half-away (add 0x8000), v_perm grabs high halves.
__device__ __forceinline__ unsigned pack2rn(float a, float b) {
    union { float f; unsigned u; } x, y; x.f = a; y.f = b;
    return __builtin_amdgcn_perm(y.u + 0x8000u, x.u + 0x8000u, 0x07060302u);
}

// async global -> LDS, 16B/lane (wave-uniform LDS base; HW adds lane*16; global addr per-lane)
__device__ __forceinline__ void gl_lds16(const void* g, void* l) {
    __builtin_amdgcn_global_load_lds(
        (const __attribute__((address_space(1))) void*)g,
        (__attribute__((address_space(3)))       void*)l, 16, 0, 0);
}

// ---------------- Pass 1: fp32 -> bf16 convert (INPUTS ONLY, ~25 MB traffic) ----------------
__global__ __launch_bounds__(256) void cvt_x(
    const float* __restrict__ x, u16* __restrict__ xbf)
{
    const size_t nch = (size_t)XEL / 8;
    for (size_t c = (size_t)blockIdx.x * blockDim.x + threadIdx.x; c < nch;
         c += (size_t)gridDim.x * blockDim.x) {
        size_t off = c * 8;
        float4 f0 = *(const float4*)(x + off);
        float4 f1 = *(const float4*)(x + off + 4);
        uint4 pk;
        pk.x = pack2rn(f0.x, f0.y); pk.y = pack2rn(f0.z, f0.w);
        pk.z = pack2rn(f1.x, f1.y); pk.w = pack2rn(f1.z, f1.w);
        *(uint4*)(xbf + off) = pk;
    }
}

// ---------------- Pass 2: 256x128 grouped GEMM (BK=32), fused W cvt ----------------
// Best-measured configuration of the session (Round 10: 104.2 us total).
// 2D super-tile per XCD: XCD x (= bid&7, HW round-robin) owns mts [3x, 3x+3)
// x all 16 n0, mt-fastest. A bf16 via global_load_lds (source-side swizzle);
// B fp32 direct, reg-staged + fused pack (write-side swizzle); counted
// double-buffer choreography; gated atomic epilogue.
__global__ __launch_bounds__(512, 4) void moe_gemm_wf2(
    const u16*   __restrict__ xb,          // [NTOK][DIN] bf16
    const float* __restrict__ wf,          // [NE][DOUT][DIN] fp32
    const int*   __restrict__ sorted_scattered_idxs,
    const int*   __restrict__ expert_offsets,
    const float* __restrict__ gates,
    float*       __restrict__ out)
{
    __shared__ u16 As[2][BM * BK];         // 16 KB each
    __shared__ u16 Bs[2][BN * BK];         // 8 KB each
    __shared__ int   s_tok[BM];
    __shared__ float s_gate[BM];

    // 2D super-tile XCD schedule:
    const int bid = blockIdx.x;
    const int xcd = bid & 7;               // HW dispatch round-robins XCDs
    const int loc = bid >> 3;              // 0..47 within this XCD
    const int mt  = xcd * 3 + (loc % 3);   // 3-mt group per XCD
    const int n0  = (loc / 3) * BN;        // 16 n0 columns per XCD

    int e = -1, m0 = 0, cnt = 0;
    {
        int acc0 = 0, prev = 0;
        for (int i = 0; i < NE; ++i) {
            int end = expert_offsets[i];
            int c = end - prev;
            int t = (c + BM - 1) / BM;
            if (mt < acc0 + t) {
                e = i; m0 = prev + (mt - acc0) * BM;
                cnt = end - m0; if (cnt > BM) cnt = BM;
                break;
            }
            acc0 += t; prev = end;
        }
    }
    if (e < 0) return;   // uniform exit before any barrier

    const int tid = threadIdx.x;
    if (tid < BM) {
        int idx = (tid < cnt) ? (m0 + tid) : m0;   // clamp ragged rows to valid gather
        int p = sorted_scattered_idxs[idx];
        s_tok[tid]  = p;
        s_gate[tid] = gates[p];
    }
    __syncthreads();

    const int wid = tid >> 6, lane = tid & 63;

    // ---- A staging (bf16, gload_lds): 2 chunks/thread/K-step, source-swizzled.
    const int arow0 = wid * 16 + (lane >> 2);          // 0..127
    const int cga   = (lane & 3) ^ ((lane >> 3) & 3);  // (row>>1)&3 == (lane>>3)&3 here
    const u16* aS0 = xb + (size_t)(s_tok[arow0] >> 1) * DIN + cga * 8;
    const u16* aS1 = xb + (size_t)(s_tok[arow0 + 128] >> 1) * DIN + cga * 8;
    const int adst0 = (wid * 16) * BK;                 // wave-uniform u16 base
    const int adst1 = (128 + wid * 16) * BK;

    // ---- B staging (fp32 weight, reg-staged): 1 row-chunk/thread (8 floats).
    const int brow = tid >> 2;                         // 0..127
    const int bch  = tid & 3;
    const int bcg  = bch ^ ((brow >> 1) & 3);          // write-side swizzle
    const float* bF = wf + (size_t)e * DOUT * DIN + (size_t)(n0 + brow) * DIN + bch * 8;
    const int bwr = brow * BK + bcg * 8;               // u16 LDS offset

    // ---- fragment geometry: wave out 128x32 at (wr*128, wc*32)
    const int wr = wid >> 2, wc = wid & 3;
    const int lr = lane & 15, g = lane >> 4;
    const int xch = (g ^ ((lr >> 1) & 3)) * 8;         // swizzled k-chunk (u16 units)
    int aoff[8], boff[2];
    #pragma unroll
    for (int mi = 0; mi < 8; ++mi) aoff[mi] = (wr * 128 + mi * 16 + lr) * BK + xch;
    #pragma unroll
    for (int n = 0; n < 2; ++n)    boff[n]  = (wc * 32 + n * 16 + lr) * BK + xch;

    f32x4 acc[8][2];
    #pragma unroll
    for (int mi = 0; mi < 8; ++mi)
        #pragma unroll
        for (int n = 0; n < 2; ++n) acc[mi][n] = (f32x4)0.0f;

    float4 pb0, pb1;   // in-flight fp32 B regs (8 floats)

#define STGA(buf, t)                                                          \
    {                                                                         \
        const int ko = (t) * BK;                                              \
        gl_lds16(aS0 + ko, &As[buf][adst0]);                                  \
        gl_lds16(aS1 + ko, &As[buf][adst1]);                                  \
    }

#define BGLB(t)                                                               \
    {                                                                         \
        const int ko = (t) * BK;                                              \
        pb0 = *(const float4*)(bF + ko);                                      \
        pb1 = *(const float4*)(bF + ko + 4);                                  \
    }

#define BPACK(buf)                                                            \
    {                                                                         \
        uint4 w;                                                              \
        w.x = pack2rn(pb0.x, pb0.y); w.y = pack2rn(pb0.z, pb0.w);             \
        w.z = pack2rn(pb1.x, pb1.y); w.w = pack2rn(pb1.z, pb1.w);             \
        *(uint4*)(&Bs[buf][bwr]) = w;                                         \
    }

#define BODY(b)                                                               \
    {                                                                         \
        bf16x8 bfv[2], af[4], ag[4];                                          \
        bfv[0] = *(const bf16x8*)(&Bs[b][boff[0]]);                           \
        bfv[1] = *(const bf16x8*)(&Bs[b][boff[1]]);                           \
        _Pragma("unroll")                                                     \
        for (int mi = 0; mi < 4; ++mi)                                        \
            af[mi] = *(const bf16x8*)(&As[b][aoff[mi]]);                      \
        __builtin_amdgcn_s_setprio(1);                                        \
        _Pragma("unroll")                                                     \
        for (int mi = 0; mi < 4; ++mi) {                                      \
            acc[mi][0] = __builtin_amdgcn_mfma_f32_16x16x32_bf16(             \
                af[mi], bfv[0], acc[mi][0], 0, 0, 0);                         \
            acc[mi][1] = __builtin_amdgcn_mfma_f32_16x16x32_bf16(             \
                af[mi], bfv[1], acc[mi][1], 0, 0, 0);                         \
        }                                                                     \
        _Pragma("unroll")                                                     \
        for (int mi = 0; mi < 4; ++mi)                                        \
            ag[mi] = *(const bf16x8*)(&As[b][aoff[mi + 4]]);                  \
        _Pragma("unroll")                                                     \
        for (int mi = 0; mi < 4; ++mi) {                                      \
            acc[mi+4][0] = __builtin_amdgcn_mfma_f32_16x16x32_bf16(           \
                ag[mi], bfv[0], acc[mi+4][0], 0, 0, 0);                       \
            acc[mi+4][1] = __builtin_amdgcn_mfma_f32_16x16x32_bf16(           \
                ag[mi], bfv[1], acc[mi+4][1], 0, 0, 0);                       \
        }                                                                     \
        __builtin_amdgcn_s_setprio(0);                                        \
        __builtin_amdgcn_s_barrier();                                         \
    }

    // ---- prologue: tile 0 to LDS (single drain), tile 1 in flight
    BGLB(0);
    STGA(0, 0);
    asm volatile("s_waitcnt vmcnt(0)" ::: "memory");
    __builtin_amdgcn_sched_barrier(0);
    BPACK(0);
    STGA(1, 1);
    BGLB(1);

    #pragma unroll 2
    for (int t = 0; t < NKT; ++t) {
        // own ds_write (BPACK at tail t-1 / prologue) retired before barrier
        asm volatile("s_waitcnt lgkmcnt(0)" ::: "memory");
        __builtin_amdgcn_s_barrier();
        BODY(t & 1);                           // ends with s_barrier
        // drain stage(t+1), issued one full body ago (latency hidden)
        asm volatile("s_waitcnt vmcnt(0)" ::: "memory");
        __builtin_amdgcn_sched_barrier(0);
        if (t + 1 < NKT) BPACK((t + 1) & 1);   // buf free: its readers done in BODY(t-1)
        if (t + 2 < NKT) { STGA(t & 1, t + 2); BGLB(t + 2); }
    }

#undef STGA
#undef BGLB
#undef BPACK
#undef BODY

    // ---- epilogue: out[token] += gate * y  (TOPK contributions accumulate)
    #pragma unroll
    for (int mi = 0; mi < 8; ++mi) {
        #pragma unroll
        for (int r = 0; r < 4; ++r) {
            int lrow = wr * 128 + mi * 16 + g * 4 + r;
            if (lrow < cnt) {
                int   p  = s_tok[lrow];
                float gf = s_gate[lrow];
                float* orow = out + (size_t)(p >> 1) * DOUT + n0 + wc * 32;
                #pragma unroll
                for (int n = 0; n < 2; ++n)
                    atomicAdd(orow + n * 16 + lr, gf * acc[mi][n][r]);
            }
        }
    }
}

// ---------------- Fallback: fully-fused fp32-in kernel (used if ws too small) ----------------
#define FBM 128
#define FBK 64
__global__ __launch_bounds__(256, 3) void moe_gemm_fused(
    const float* __restrict__ inputs, const float* __restrict__ weight,
    const int* __restrict__ sorted_scattered_idxs, const int* __restrict__ expert_offsets,
    const float* __restrict__ gates, float* __restrict__ out)
{
    __shared__ u16 As[FBM * FBK];
    __shared__ u16 Bs[FBM * FBK];
    __shared__ int   s_tok[FBM];
    __shared__ float s_gate[FBM];

    const int mt = blockIdx.y;
    const int n0 = blockIdx.x * FBM;
    int e = -1, m0 = 0, cnt = 0;
    {
        int acc = 0, prev = 0;
        for (int i = 0; i < NE; ++i) {
            int end = expert_offsets[i];
            int c = end - prev;
            int t = (c + FBM - 1) / FBM;
            if (mt < acc + t) {
                e = i; m0 = prev + (mt - acc) * FBM;
                cnt = end - m0; if (cnt > FBM) cnt = FBM;
                break;
            }
            acc += t; prev = end;
        }
    }
    if (e < 0) return;

    const int tid = threadIdx.x;
    if (tid < FBM) {
        int idx = (tid < cnt) ? (m0 + tid) : m0;
        int p = sorted_scattered_idxs[idx];
        s_tok[tid]  = p;
        s_gate[tid] = gates[p];
    }
    __syncthreads();

    const int ch  = tid & 7;
    const int r0  = tid >> 3;
    const int sch = ch ^ (r0 & 7);
    const float* wbase = weight + (size_t)e * DOUT * DIN;
    const float* ap[4]; const float* bp[4];
    #pragma unroll
    for (int i = 0; i < 4; ++i) {
        int r = r0 + 32 * i;
        ap[i] = inputs + (size_t)(s_tok[r] >> 1) * DIN + ch * 8;
        bp[i] = wbase + (size_t)(n0 + r) * DIN + ch * 8;
    }
    u16* aw = &As[r0 * FBK + sch * 8];
    u16* bw = &Bs[r0 * FBK + sch * 8];

    const int wid = tid >> 6, lane = tid & 63;
    const int wm = (wid >> 1) * 64, wn = (wid & 1) * 64;
    const int g  = lane >> 4, lr = lane & 15;

    f32x4 acc[4][4];
    #pragma unroll
    for (int i = 0; i < 4; ++i)
        #pragma unroll
        for (int j = 0; j < 4; ++j) acc[i][j] = (f32x4)0.0f;

    float4 pa[4][2], pb[4][2];
    #pragma unroll
    for (int i = 0; i < 4; ++i) {
        pa[i][0] = *(const float4*)(ap[i] + 0); pa[i][1] = *(const float4*)(ap[i] + 4);
        pb[i][0] = *(const float4*)(bp[i] + 0); pb[i][1] = *(const float4*)(bp[i] + 4);
    }
    for (int kt = 0; kt < DIN / FBK; ++kt) {
        __syncthreads();
        #pragma unroll
        for (int i = 0; i < 4; ++i) {
            uint4 va, vb;
            va.x = pack2rn(pa[i][0].x, pa[i][0].y); va.y = pack2rn(pa[i][0].z, pa[i][0].w);
            va.z = pack2rn(pa[i][1].x, pa[i][1].y); va.w = pack2rn(pa[i][1].z, pa[i][1].w);
            *(uint4*)(aw + i * 32 * FBK) = va;
            vb.x = pack2rn(pb[i][0].x, pb[i][0].y); vb.y = pack2rn(pb[i][0].z, pb[i][0].w);
            vb.z = pack2rn(pb[i][1].x, pb[i][1].y); vb.w = pack2rn(pb[i][1].z, pb[i][1].w);
            *(uint4*)(bw + i * 32 * FBK) = vb;
        }
        __syncthreads();
        if (kt + 1 < DIN / FBK) {
            const int kof = (kt + 1) * FBK;
            #pragma unroll
            for (int i = 0; i < 4; ++i) {
                pa[i][0] = *(const float4*)(ap[i] + kof); pa[i][1] = *(const float4*)(ap[i] + kof + 4);
                pb[i][0] = *(const float4*)(bp[i] + kof); pb[i][1] = *(const float4*)(bp[i] + kof + 4);
            }
        }
        #pragma unroll
        for (int ks = 0; ks < 2; ++ks) {
            bf16x8 a[4], b[4];
            #pragma unroll
            for (int i = 0; i < 4; ++i) {
                int ra = wm + i * 16 + lr; int ca = (ks * 4 + g) ^ (ra & 7);
                a[i] = *(const bf16x8*)(&As[ra * FBK + ca * 8]);
                int rb = wn + i * 16 + lr; int cb = (ks * 4 + g) ^ (rb & 7);
                b[i] = *(const bf16x8*)(&Bs[rb * FBK + cb * 8]);
            }
            #pragma unroll
            for (int i = 0; i < 4; ++i)
                #pragma unroll
                for (int j = 0; j < 4; ++j)
                    acc[i][j] = __builtin_amdgcn_mfma_f32_16x16x32_bf16(a[i], b[j], acc[i][j], 0, 0, 0);
        }
    }
    #pragma unroll
    for (int i = 0; i < 4; ++i) {
        #pragma unroll
        for (int j2 = 0; j2 < 4; ++j2) {
            int lrow = wm + i * 16 + g * 4 + j2;
            if (lrow < cnt) {
                int   p  = s_tok[lrow];
                float gf = s_gate[lrow];
                float* orow = out + (size_t)(p >> 1) * DOUT + n0 + wn;
                #pragma unroll
                for (int nf = 0; nf < 4; ++nf)
                    atomicAdd(orow + nf * 16 + lr, gf * acc[i][nf][j2]);
            }
        }
    }
}

extern "C" void kernel_launch(void* const* d_in, const int* in_sizes, int n_in,
                              void* d_out, int out_size, void* d_ws, size_t ws_size,
                              hipStream_t stream) {
    const float* inputs  = (const float*)d_in[0];
    const float* weight  = (const float*)d_in[1];
    const int*   ssi     = (const int*)d_in[4];
    const int*   eoff    = (const int*)d_in[6];
    const float* gates   = (const float*)d_in[7];
    float* out = (float*)d_out;

    hipMemsetAsync(out, 0, (size_t)out_size * sizeof(float), stream);

    const size_t need = (size_t)XEL * sizeof(u16);   // 8.4 MB (inputs only)
    if (ws_size >= need) {
        u16* xbf = (u16*)d_ws;
        cvt_x<<<1024, 256, 0, stream>>>(inputs, xbf);
        moe_gemm_wf2<<<NBLK, 512, 0, stream>>>(xbf, weight, ssi, eoff, gates, out);
    } else {
        dim3 grid(DOUT / FBM, NK / FBM + NE);
        moe_gemm_fused<<<grid, 256, 0, stream>>>(inputs, weight, ssi, eoff, gates, out);
    }
}